// Round 7
// baseline (700.286 us; speedup 1.0000x reference)
//
#include <hip/hip_runtime.h>
#include <hip/hip_bf16.h>

typedef __attribute__((ext_vector_type(4))) float f32x4;
typedef __bf16 bf16x8 __attribute__((ext_vector_type(8)));
typedef int int4v __attribute__((ext_vector_type(4)));

#define TOKENS 16384
#define DIM    2048
#define NKVQ   3072

__device__ __forceinline__ void gload_lds16(const void* g, void* l) {
  __builtin_amdgcn_global_load_lds((const __attribute__((address_space(1))) void*)g,
                                   (__attribute__((address_space(3))) void*)l, 16, 0, 0);
}

// ---------------- cast fp32 -> bf16, 8 elems/thread ----------------
__global__ void cast8_kernel(const float* __restrict__ src, __bf16* __restrict__ dst, int n8) {
  int i = blockIdx.x * blockDim.x + threadIdx.x;
  if (i >= n8) return;
  const float4* s = (const float4*)src;
  float4 a = s[2 * i], b = s[2 * i + 1];
  bf16x8 o;
  o[0] = (__bf16)a.x; o[1] = (__bf16)a.y; o[2] = (__bf16)a.z; o[3] = (__bf16)a.w;
  o[4] = (__bf16)b.x; o[5] = (__bf16)b.y; o[6] = (__bf16)b.z; o[7] = (__bf16)b.w;
  ((bf16x8*)dst)[i] = o;
}

// ---------------- Weff[d, h*64+k] = sum_v Wo[d, h*64+v] * mem[h,k,v] ----------------
__global__ void weff_kernel(const float* __restrict__ Wo, const float* __restrict__ mem,
                            __bf16* __restrict__ Weff) {
  int idx = blockIdx.x * blockDim.x + threadIdx.x;  // 2048*1024
  int d = idx >> 10, hk = idx & 1023, h = hk >> 6;
  const float* wo = Wo + d * 1024 + h * 64;
  const float* mm = mem + hk * 64;
  float s = 0.f;
  #pragma unroll 8
  for (int v = 0; v < 64; ++v) s += wo[v] * mm[v];
  Weff[idx] = (__bf16)s;
}

// ================= 256x256 MFMA core, 4 fat waves, BK=32, 4-buf ring (C = A @ B^T) ============
// 256 threads = 4 waves (2x2); per-wave 128x128 output; acc[8][8] f32x4 (AGPR).
// LDS 128KB = 4 bufs x (A 16KB + B 16KB). Tile: 256 rows x K=32, row-major 64B/row.
// Swizzle (16B units): phys = u ^ ((u>>3)&7) (involution; pre-swizzled global src, swizzled reads).
// Read-ahead pipeline: phase t = { ds_read tile t+1 frags -> shadow regs | stage tile t+3 |
//   MFMA x64 on tile t regs | vmcnt(8) | barrier }.  LDS pipe overlaps MFMA pipe.
__device__ __forceinline__ void gemm256_core(
    const __bf16* __restrict__ A, int lda,
    const __bf16* __restrict__ B, int ldb,
    int m0, int n0, int nt, char* sm, f32x4 acc[8][8]) {

  const int tid = threadIdx.x, lane = tid & 63, wid = tid >> 6;
  const int wr = wid >> 1, wc = wid & 1;
  const int lrow = lane & 15, kc = lane >> 4;

  int offA[8], offB[8];
  #pragma unroll
  for (int m = 0; m < 8; ++m) {
    int u = (wr * 128 + m * 16 + lrow) * 4 + kc;
    offA[m] = (u ^ ((u >> 3) & 7)) << 4;
  }
  #pragma unroll
  for (int n = 0; n < 8; ++n) {
    int u = (wc * 128 + n * 16 + lrow) * 4 + kc;
    offB[n] = ((u ^ ((u >> 3) & 7)) << 4) + 16384;
  }

  const __bf16* pSA[4]; const __bf16* pSB[4];
  #pragma unroll
  for (int s = 0; s < 4; ++s) {
    int U = s * 256 + tid;
    int u = U ^ ((U >> 3) & 7);
    pSA[s] = A + (size_t)(m0 + (u >> 2)) * lda + (u & 3) * 8;
    pSB[s] = B + (size_t)(n0 + (u >> 2)) * ldb + (u & 3) * 8;
  }

  bf16x8 avSA[8], avSB[8], bvSA[8], bvSB[8];

#define BARX() asm volatile("s_barrier" ::: "memory")
#define VM8()  asm volatile("s_waitcnt vmcnt(8)" ::: "memory")
#define VM0()  asm volatile("s_waitcnt vmcnt(0)" ::: "memory")
#define NOVM
#define NOSTAGE
#define STAGE(bb, tt) do { \
    char* sA = sm + (bb) * 32768 + tid * 16; \
    gload_lds16(pSA[0] + (tt) * 32, sA); \
    gload_lds16(pSA[1] + (tt) * 32, sA + 4096); \
    gload_lds16(pSA[2] + (tt) * 32, sA + 8192); \
    gload_lds16(pSA[3] + (tt) * 32, sA + 12288); \
    gload_lds16(pSB[0] + (tt) * 32, sA + 16384); \
    gload_lds16(pSB[1] + (tt) * 32, sA + 20480); \
    gload_lds16(pSB[2] + (tt) * 32, sA + 24576); \
    gload_lds16(pSB[3] + (tt) * 32, sA + 28672); } while (0)

// PH: read tile-ahead frags from bufN into set N; stage; MFMA on set C; wait; barrier.
#define PH(bufN, C, N, STG, WT) do { \
    const char* bN = sm + (bufN) * 32768; \
    _Pragma("unroll") for (int m = 0; m < 8; ++m) avS##N[m] = *(const bf16x8*)(bN + offA[m]); \
    _Pragma("unroll") for (int n = 0; n < 8; ++n) bvS##N[n] = *(const bf16x8*)(bN + offB[n]); \
    STG; \
    __builtin_amdgcn_sched_barrier(0); \
    __builtin_amdgcn_s_setprio(1); \
    _Pragma("unroll") for (int m = 0; m < 8; ++m) \
      _Pragma("unroll") for (int n = 0; n < 8; ++n) \
        acc[m][n] = __builtin_amdgcn_mfma_f32_16x16x32_bf16(avS##C[m], bvS##C[n], acc[m][n], 0, 0, 0); \
    __builtin_amdgcn_s_setprio(0); \
    WT; BARX(); } while (0)

#define PHF(C) do { \
    __builtin_amdgcn_s_setprio(1); \
    _Pragma("unroll") for (int m = 0; m < 8; ++m) \
      _Pragma("unroll") for (int n = 0; n < 8; ++n) \
        acc[m][n] = __builtin_amdgcn_mfma_f32_16x16x32_bf16(avS##C[m], bvS##C[n], acc[m][n], 0, 0, 0); \
    __builtin_amdgcn_s_setprio(0); } while (0)

  // prologue: stage tiles 0,1,2 (24 loads); VM8 -> tiles 0,1 resident; preload tile0 -> set A
  STAGE(0, 0); STAGE(1, 1); STAGE(2, 2);
  VM8(); BARX();
  #pragma unroll
  for (int m = 0; m < 8; ++m) avSA[m] = *(const bf16x8*)(sm + offA[m]);
  #pragma unroll
  for (int n = 0; n < 8; ++n) bvSA[n] = *(const bf16x8*)(sm + offB[n]);

  // main loop: phases 0..nt-5 (4 per iter). Phase t: read tile t+1, stage tile t+3, MFMA tile t.
  for (int i = 0, e = (nt - 4) >> 2; i < e; ++i) {
    const int t = i << 2;
    PH(1, A, B, STAGE(3, t + 3), VM8());
    PH(2, B, A, STAGE(0, t + 4), VM8());
    PH(3, A, B, STAGE(1, t + 5), VM8());
    PH(0, B, A, STAGE(2, t + 6), VM8());
  }
  // tail: phases nt-4 .. nt-1 (bufs 0..3, cur set A at nt-4 since nt%4==0)
  PH(1, A, B, STAGE(3, nt - 1), VM8());
  PH(2, B, A, NOSTAGE, VM0());
  PH(3, A, B, NOSTAGE, NOVM);
  PHF(B);
#undef PH
#undef PHF
#undef STAGE
#undef BARX
#undef VM8
#undef VM0
#undef NOVM
#undef NOSTAGE
}

// ---------------- GEMM1: [Y | sigmoid-gate] = Xb @ [Wk;Wv;Wq;Wg]^T  (N = 5120) ----------------
__global__ void __launch_bounds__(256, 1)
gemm_fused_kernel(const __bf16* __restrict__ Xb, const __bf16* __restrict__ W1,
                  __bf16* __restrict__ Y, __bf16* __restrict__ Gb) {
  __shared__ __attribute__((aligned(16))) char smem[131072];
  const int x = blockIdx.x & 7;       // XCD
  const int l = blockIdx.x >> 3;      // 0..159
  const int bm = x * 8 + (l & 7);     // bm owned by one XCD
  const int bn = l >> 3;              // concurrent blocks share bn
  const int m0 = bm * 256, n0 = bn * 256;
  f32x4 acc[8][8] = {};
  gemm256_core(Xb, DIM, W1, DIM, m0, n0, 64, smem, acc);

  // epilogue: acc -> LDS (bf16, swizzled 16B slots) -> wide NT stores
  __syncthreads();
  const int tid = threadIdx.x, wid = tid >> 6, lane = tid & 63;
  const int wr = wid >> 1, wc = wid & 1;
  const int crow = (lane >> 4) << 2, ccol = lane & 15;
  const bool isY = bn < 12;
  #pragma unroll
  for (int f = 0; f < 8; ++f)
    #pragma unroll
    for (int n = 0; n < 8; ++n)
      #pragma unroll
      for (int j = 0; j < 4; ++j) {
        int r = wr * 128 + f * 16 + crow + j;
        int c = wc * 128 + n * 16 + ccol;
        float v = acc[f][n][j];
        if (!isY) v = 1.0f / (1.0f + __expf(-v));
        *(__bf16*)(smem + r * 512 + ((c * 2) ^ ((r & 7) << 4))) = (__bf16)v;
      }
  __syncthreads();
  const int rsub = tid >> 5, ch = tid & 31;
  if (isY) {
    #pragma unroll
    for (int p = 0; p < 32; ++p) {
      int r = p * 8 + rsub;
      bf16x8 v = *(const bf16x8*)(smem + r * 512 + ((ch * 16) ^ ((r & 7) << 4)));
      __builtin_nontemporal_store(__builtin_bit_cast(int4v, v),
          (int4v*)(Y + (size_t)(m0 + r) * NKVQ + n0 + ch * 8));
    }
  } else {
    const int c0 = n0 - 3072;
    #pragma unroll
    for (int p = 0; p < 32; ++p) {
      int r = p * 8 + rsub;
      bf16x8 v = *(const bf16x8*)(smem + r * 512 + ((ch * 16) ^ ((r & 7) << 4)));
      __builtin_nontemporal_store(__builtin_bit_cast(int4v, v),
          (int4v*)(Gb + (size_t)(m0 + r) * DIM + c0 + ch * 8));
    }
  }
}

// ---------------- GEMM2: out = hidden + Gb * (Q @ Weff^T)   (K = 1024) ----------------
__global__ void __launch_bounds__(256, 1)
gemm_read_kernel(const __bf16* __restrict__ Yq, const __bf16* __restrict__ Weff,
                 const __bf16* __restrict__ Gb, const float* __restrict__ hidden,
                 float* __restrict__ out) {
  __shared__ __attribute__((aligned(16))) char smem[131072];
  const int x = blockIdx.x & 7;
  const int l = blockIdx.x >> 3;      // 0..63
  const int bm = x * 8 + (l & 7);
  const int bn = l >> 3;              // 0..7
  const int m0 = bm * 256, n0 = bn * 256;
  f32x4 acc[8][8] = {};
  gemm256_core(Yq, NKVQ, Weff, 1024, m0, n0, 32, smem, acc);

  const int tid = threadIdx.x, wid = tid >> 6, lane = tid & 63;
  const int wr = wid >> 1, wc = wid & 1;
  const int crow = (lane >> 4) << 2, ccol = lane & 15;
  #pragma unroll
  for (int f = 0; f < 8; ++f) {
    int row = m0 + wr * 128 + f * 16 + crow;
    #pragma unroll
    for (int n = 0; n < 8; ++n) {
      int col = n0 + wc * 128 + n * 16 + ccol;
      #pragma unroll
      for (int j = 0; j < 4; ++j) {
        size_t idx = (size_t)(row + j) * DIM + col;
        out[idx] = hidden[idx] + (float)Gb[idx] * acc[f][n][j];
      }
    }
  }
}

// ---------------- memory update partials: part[sp][h] += K_h^T V_h over 1024 tokens ----------------
__global__ void __launch_bounds__(256)
mem_update_kernel(const __bf16* __restrict__ Y, float* __restrict__ part) {
  const int h = blockIdx.x & 15, sp = blockIdx.x >> 4;
  __shared__ __attribute__((aligned(16))) __bf16 KT[64 * 32];
  __shared__ __attribute__((aligned(16))) __bf16 VT[64 * 32];
  const int tid = threadIdx.x, wid = tid >> 6, lane = tid & 63;
  const int lrow = lane & 15, lk = (lane >> 4) * 8;
  const __bf16* Kbase = Y + (size_t)sp * 1024 * NKVQ + h * 64;
  const __bf16* Vbase = Kbase + 1024;
  f32x4 acc[4] = {};
  const int t = tid >> 3, c8 = (tid & 7) * 8;
  for (int t0 = 0; t0 < 1024; t0 += 32) {
    __syncthreads();
    bf16x8 kv = *(const bf16x8*)(Kbase + (size_t)(t0 + t) * NKVQ + c8);
    bf16x8 vv = *(const bf16x8*)(Vbase + (size_t)(t0 + t) * NKVQ + c8);
    #pragma unroll
    for (int j = 0; j < 8; ++j) {
      KT[(c8 + j) * 32 + t] = kv[j];
      VT[(c8 + j) * 32 + t] = vv[j];
    }
    __syncthreads();
    bf16x8 af = *(const bf16x8*)(KT + (wid * 16 + lrow) * 32 + lk);
    #pragma unroll
    for (int n = 0; n < 4; ++n) {
      bf16x8 bf_ = *(const bf16x8*)(VT + (n * 16 + lrow) * 32 + lk);
      acc[n] = __builtin_amdgcn_mfma_f32_16x16x32_bf16(af, bf_, acc[n], 0, 0, 0);
    }
  }
  float* pp = part + ((size_t)sp * 16 + h) * 4096;
  const int crow = wid * 16 + (lane >> 4) * 4, ccol = lane & 15;
  #pragma unroll
  for (int n = 0; n < 4; ++n)
    #pragma unroll
    for (int r = 0; r < 4; ++r)
      pp[(crow + r) * 64 + n * 16 + ccol] = acc[n][r];
}

// ---------------- memory reduce: out = 0.99*mem + sum_sp part ----------------
__global__ void mem_reduce_kernel(const float* __restrict__ part, const float* __restrict__ mem,
                                  float* __restrict__ out) {
  int i = blockIdx.x * blockDim.x + threadIdx.x;
  float s = 0.99f * mem[i];
  #pragma unroll
  for (int sp = 0; sp < 16; ++sp) s += part[sp * 65536 + i];
  out[i] = s;
}

extern "C" void kernel_launch(void* const* d_in, const int* in_sizes, int n_in,
                              void* d_out, int out_size, void* d_ws, size_t ws_size,
                              hipStream_t stream) {
  const float* hidden = (const float*)d_in[0];
  const float* memory = (const float*)d_in[1];
  const float* Wk = (const float*)d_in[2];
  const float* Wv = (const float*)d_in[3];
  const float* Wq = (const float*)d_in[4];
  const float* Wg = (const float*)d_in[5];
  const float* Wo = (const float*)d_in[6];
  float* out = (float*)d_out;
  float* mem_out = out + (size_t)TOKENS * DIM;

  char* ws = (char*)d_ws;
  __bf16* Xb   = (__bf16*)(ws);                    // 16384x2048  (67,108,864 B)
  __bf16* W1   = (__bf16*)(ws + 67108864);         // 5120x2048   (20,971,520 B)
  __bf16* Weff = (__bf16*)(ws + 88080384);         // 2048x1024   ( 4,194,304 B)
  __bf16* Yb   = (__bf16*)(ws + 92274688);         // 16384x3072  (100,663,296 B)
  __bf16* Gb   = (__bf16*)(ws + 192937984);        // 16384x2048  (67,108,864 B)
  float*  part = (float*)(ws + 260046848);         // 16x16x64x64 ( 4,194,304 B)

  cast8_kernel<<<16384, 256, 0, stream>>>(hidden, Xb, 4194304);
  cast8_kernel<<<1024, 256, 0, stream>>>(Wk, W1, 262144);
  cast8_kernel<<<1024, 256, 0, stream>>>(Wv, W1 + 2097152, 262144);
  cast8_kernel<<<1024, 256, 0, stream>>>(Wq, W1 + 4194304, 262144);
  cast8_kernel<<<2048, 256, 0, stream>>>(Wg, W1 + 6291456, 524288);
  weff_kernel<<<8192, 256, 0, stream>>>(Wo, memory, Weff);

  gemm_fused_kernel<<<1280, 256, 0, stream>>>(Xb, W1, Yb, Gb);
  gemm_read_kernel<<<512, 256, 0, stream>>>(Yb + 2048, Weff, Gb, hidden, out);

  mem_update_kernel<<<256, 256, 0, stream>>>(Yb, part);
  mem_reduce_kernel<<<256, 256, 0, stream>>>(part, memory, mem_out);
}

// Round 9
// 605.933 us; speedup vs baseline: 1.1557x; 1.1557x over previous
//
#include <hip/hip_runtime.h>
#include <hip/hip_bf16.h>

typedef __attribute__((ext_vector_type(4))) float f32x4;
typedef __bf16 bf16x8 __attribute__((ext_vector_type(8)));
typedef int int4v __attribute__((ext_vector_type(4)));

#define TOKENS 16384
#define DIM    2048
#define NKVQ   3072

__device__ __forceinline__ void gload_lds16(const void* g, void* l) {
  __builtin_amdgcn_global_load_lds((const __attribute__((address_space(1))) void*)g,
                                   (__attribute__((address_space(3))) void*)l, 16, 0, 0);
}

// ---------------- cast fp32 -> bf16, 8 elems/thread ----------------
__global__ void cast8_kernel(const float* __restrict__ src, __bf16* __restrict__ dst, int n8) {
  int i = blockIdx.x * blockDim.x + threadIdx.x;
  if (i >= n8) return;
  const float4* s = (const float4*)src;
  float4 a = s[2 * i], b = s[2 * i + 1];
  bf16x8 o;
  o[0] = (__bf16)a.x; o[1] = (__bf16)a.y; o[2] = (__bf16)a.z; o[3] = (__bf16)a.w;
  o[4] = (__bf16)b.x; o[5] = (__bf16)b.y; o[6] = (__bf16)b.z; o[7] = (__bf16)b.w;
  ((bf16x8*)dst)[i] = o;
}

// ---------------- Weff[d, h*64+k] = sum_v Wo[d, h*64+v] * mem[h,k,v] ----------------
__global__ void weff_kernel(const float* __restrict__ Wo, const float* __restrict__ mem,
                            __bf16* __restrict__ Weff) {
  int idx = blockIdx.x * blockDim.x + threadIdx.x;  // 2048*1024
  int d = idx >> 10, hk = idx & 1023, h = hk >> 6;
  const float* wo = Wo + d * 1024 + h * 64;
  const float* mm = mem + hk * 64;
  float s = 0.f;
  #pragma unroll 8
  for (int v = 0; v < 64; ++v) s += wo[v] * mm[v];
  Weff[idx] = (__bf16)s;
}

// ============ 256x256 MFMA core, BK=64, 2-buf, 4-quadrant phases (C = A @ B^T) ================
// 512 threads = 8 waves (2 wave-rows x 4 wave-cols); per-wave 128x64 out; acc[8][4] f32x4.
// LDS 128KB = 2 bufs x (A 32KB + B 32KB). Tile rows PERMUTED so staged quarters == read quadrants:
//   A local row = mh*128 + wr*64 + (f*16+lrow)   (quarter A_h = mh=h rows of BOTH wave-rows)
//   B local row = nh*128 + wc*32 + (nl*16+lrow)  (quarter B_h = nh=h rows of ALL wave-cols)
// Swizzle (16B slots within 128B row): phys_slot = slot ^ (local_row & 7); involution; staging
// sources pre-swizzled so linear gload_lds dest lands swizzled.
// Per K-tile: quadrants (mh,nh) = (0,0),(0,1),(1,1),(1,0); each fragment ds_read ONCE, reused by
// 2 quadrants. Each phase stages one quarter of tile t+1 (2 gload_lds). vmcnt(2) at P0/P3 ends
// only (ledger: every quarter's loads retire before its first read; never drains mid-loop).
__device__ __forceinline__ void gemm256_core(
    const __bf16* __restrict__ A, int lda,
    const __bf16* __restrict__ B, int ldb,
    int m0, int n0, int nt, char* sm, f32x4 acc[8][4]) {

  const int tid = threadIdx.x, lane = tid & 63, wid = tid >> 6;
  const int wr = wid >> 2, wc = wid & 3;
  const int lrow = lane & 15, kc = lane >> 4, s7 = lrow & 7;

  const int rowA = (wr * 64 + lrow) * 128;            // A-region byte base (local, permuted)
  const int rowB = (wc * 32 + lrow) * 128 + 32768;    // B-region
  const int sw0 = ((0 + kc) ^ s7) << 4;               // kk=0 swizzled slot
  const int sw1 = ((4 + kc) ^ s7) << 4;               // kk=1

  // staging source byte-offsets for quarter (half h, load L); dest unit l = h*1024+L*512+tid
  unsigned oa[2][2], ob[2][2];
  #pragma unroll
  for (int h = 0; h < 2; ++h)
    #pragma unroll
    for (int L = 0; L < 2; ++L) {
      int l = h * 1024 + L * 512 + tid;
      int rl = l >> 3;                            // local row
      int c  = (l & 7) ^ (rl & 7);                // pre-swizzled 16B slot
      int ra = ((rl & 127) >> 6) * 128 + h * 64 + (rl & 63);   // global A row (inverse perm)
      int rb = ((rl & 127) >> 5) * 64  + h * 32 + (rl & 31);   // global B row (inverse perm)
      oa[h][L] = (unsigned)(((m0 + ra) * lda + c * 8) * 2);
      ob[h][L] = (unsigned)(((n0 + rb) * ldb + c * 8) * 2);
    }
  const char* Ab = (const char*)A;
  const char* Bb = (const char*)B;

  bf16x8 avA[4][2], avB[4][2], bvA[2][2], bvB[2][2];

#define BARX() asm volatile("s_barrier" ::: "memory")
#define VM2()  asm volatile("s_waitcnt vmcnt(2)" ::: "memory")
#define VM0()  asm volatile("s_waitcnt vmcnt(0)" ::: "memory")
#define STA(bb, h, tt) do { \
    gload_lds16(Ab + oa[h][0] + (tt) * 128, sm + (bb) * 65536 + ((h) * 1024 + tid) * 16); \
    gload_lds16(Ab + oa[h][1] + (tt) * 128, sm + (bb) * 65536 + ((h) * 1024 + 512 + tid) * 16); } while (0)
#define STB(bb, h, tt) do { \
    gload_lds16(Bb + ob[h][0] + (tt) * 128, sm + (bb) * 65536 + 32768 + ((h) * 1024 + tid) * 16); \
    gload_lds16(Bb + ob[h][1] + (tt) * 128, sm + (bb) * 65536 + 32768 + ((h) * 1024 + 512 + tid) * 16); } while (0)
#define RD_AV(dst, bb, mh) \
    _Pragma("unroll") for (int f = 0; f < 4; ++f) { \
      dst[f][0] = *(const bf16x8*)(sm + (bb) * 65536 + (mh) * 16384 + rowA + f * 2048 + sw0); \
      dst[f][1] = *(const bf16x8*)(sm + (bb) * 65536 + (mh) * 16384 + rowA + f * 2048 + sw1); }
#define RD_BV(dst, bb, nh) \
    _Pragma("unroll") for (int n = 0; n < 2; ++n) { \
      dst[n][0] = *(const bf16x8*)(sm + (bb) * 65536 + (nh) * 16384 + rowB + n * 2048 + sw0); \
      dst[n][1] = *(const bf16x8*)(sm + (bb) * 65536 + (nh) * 16384 + rowB + n * 2048 + sw1); }
#define MM(av, bv, fo, no) do { \
    __builtin_amdgcn_s_setprio(1); \
    _Pragma("unroll") for (int f = 0; f < 4; ++f) \
      _Pragma("unroll") for (int n = 0; n < 2; ++n) { \
        acc[(fo) + f][(no) + n] = __builtin_amdgcn_mfma_f32_16x16x32_bf16(av[f][0], bv[n][0], acc[(fo) + f][(no) + n], 0, 0, 0); \
        acc[(fo) + f][(no) + n] = __builtin_amdgcn_mfma_f32_16x16x32_bf16(av[f][1], bv[n][1], acc[(fo) + f][(no) + n], 0, 0, 0); } \
    __builtin_amdgcn_s_setprio(0); } while (0)

// one K-tile computing buf c, staging tile t+1 into buf d
#define TILE_PH(c, d, t) do { \
    RD_AV(avA, c, 0); RD_BV(bvA, c, 0); \
    STA(d, 0, (t) + 1); \
    BARX(); \
    MM(avA, bvA, 0, 0); \
    VM2(); BARX(); \
    RD_BV(bvB, c, 1); \
    STA(d, 1, (t) + 1); \
    BARX(); \
    MM(avA, bvB, 0, 2); \
    BARX(); \
    RD_AV(avB, c, 1); \
    STB(d, 0, (t) + 1); \
    BARX(); \
    MM(avB, bvB, 4, 2); \
    BARX(); \
    STB(d, 1, (t) + 1); \
    BARX(); \
    MM(avB, bvA, 4, 0); \
    VM2(); BARX(); } while (0)

// last K-tile: no staging; VM0 before reading the B1 quarter (<=2 outstanding, cheap)
#define TILE_TAIL(c) do { \
    RD_AV(avA, c, 0); RD_BV(bvA, c, 0); \
    BARX(); \
    MM(avA, bvA, 0, 0); \
    VM0(); \
    RD_BV(bvB, c, 1); \
    MM(avA, bvB, 0, 2); \
    RD_AV(avB, c, 1); \
    MM(avB, bvB, 4, 2); \
    MM(avB, bvA, 4, 0); } while (0)

  // prologue: stage tile0 quarters A0,A1,B0,B1 into buf0; VM2 -> A0,A1,B0 landed (B1 may fly)
  STA(0, 0, 0); STA(0, 1, 0); STB(0, 0, 0); STB(0, 1, 0);
  VM2(); BARX();

  for (int i = 0, e = (nt - 2) >> 1; i < e; ++i) {
    const int t = i << 1;
    TILE_PH(0, 1, t);
    TILE_PH(1, 0, t + 1);
  }
  TILE_PH(0, 1, nt - 2);
  TILE_TAIL(1);
#undef TILE_PH
#undef TILE_TAIL
#undef MM
#undef RD_AV
#undef RD_BV
#undef STA
#undef STB
#undef BARX
#undef VM2
#undef VM0
}

// ---------------- GEMM1: [Y | sigmoid-gate] = Xb @ [Wk;Wv;Wq;Wg]^T  (N = 5120) ----------------
__global__ void __launch_bounds__(512, 1)
gemm_fused_kernel(const __bf16* __restrict__ Xb, const __bf16* __restrict__ W1,
                  __bf16* __restrict__ Y, __bf16* __restrict__ Gb) {
  __shared__ __attribute__((aligned(16))) char smem[131072];
  const int x = blockIdx.x & 7;       // XCD
  const int l = blockIdx.x >> 3;      // 0..159
  const int bm = x * 8 + (l & 7);     // bm owned by one XCD
  const int bn = l >> 3;              // concurrent blocks share bn
  const int m0 = bm * 256, n0 = bn * 256;
  f32x4 acc[8][4] = {};
  gemm256_core(Xb, DIM, W1, DIM, m0, n0, 32, smem, acc);

  // epilogue: acc -> LDS (bf16, swizzled 16B slots) -> wide NT stores
  __syncthreads();
  const int tid = threadIdx.x, wid = tid >> 6, lane = tid & 63;
  const int wr = wid >> 2, wc = wid & 3;
  const int crow = (lane >> 4) << 2, ccol = lane & 15;
  const bool isY = bn < 12;
  #pragma unroll
  for (int f = 0; f < 8; ++f)
    #pragma unroll
    for (int n = 0; n < 4; ++n)
      #pragma unroll
      for (int j = 0; j < 4; ++j) {
        int r = wr * 128 + f * 16 + crow + j;
        int c = wc * 64 + n * 16 + ccol;
        float v = acc[f][n][j];
        if (!isY) v = 1.0f / (1.0f + __expf(-v));
        *(__bf16*)(smem + r * 512 + ((c * 2) ^ ((r & 7) << 4))) = (__bf16)v;
      }
  __syncthreads();
  const int rsub = tid >> 5, ch = tid & 31;
  if (isY) {
    #pragma unroll
    for (int p = 0; p < 16; ++p) {
      int r = p * 16 + rsub;
      bf16x8 v = *(const bf16x8*)(smem + r * 512 + ((ch * 16) ^ ((r & 7) << 4)));
      __builtin_nontemporal_store(__builtin_bit_cast(int4v, v),
          (int4v*)(Y + (size_t)(m0 + r) * NKVQ + n0 + ch * 8));
    }
  } else {
    const int c0 = n0 - 3072;
    #pragma unroll
    for (int p = 0; p < 16; ++p) {
      int r = p * 16 + rsub;
      bf16x8 v = *(const bf16x8*)(smem + r * 512 + ((ch * 16) ^ ((r & 7) << 4)));
      __builtin_nontemporal_store(__builtin_bit_cast(int4v, v),
          (int4v*)(Gb + (size_t)(m0 + r) * DIM + c0 + ch * 8));
    }
  }
}

// ---------------- GEMM2: out = hidden + Gb * (Q @ Weff^T)   (K = 1024) ----------------
__global__ void __launch_bounds__(512, 1)
gemm_read_kernel(const __bf16* __restrict__ Yq, const __bf16* __restrict__ Weff,
                 const __bf16* __restrict__ Gb, const float* __restrict__ hidden,
                 float* __restrict__ out) {
  __shared__ __attribute__((aligned(16))) char smem[131072];
  const int x = blockIdx.x & 7;
  const int l = blockIdx.x >> 3;      // 0..63
  const int bm = x * 8 + (l & 7);
  const int bn = l >> 3;              // 0..7
  const int m0 = bm * 256, n0 = bn * 256;
  f32x4 acc[8][4] = {};
  gemm256_core(Yq, NKVQ, Weff, 1024, m0, n0, 16, smem, acc);

  const int tid = threadIdx.x, wid = tid >> 6, lane = tid & 63;
  const int wr = wid >> 2, wc = wid & 3;
  const int crow = (lane >> 4) << 2, ccol = lane & 15;
  #pragma unroll
  for (int f = 0; f < 8; ++f) {
    int row = m0 + wr * 128 + f * 16 + crow;
    #pragma unroll
    for (int n = 0; n < 4; ++n) {
      int col = n0 + wc * 64 + n * 16 + ccol;
      #pragma unroll
      for (int j = 0; j < 4; ++j) {
        size_t idx = (size_t)(row + j) * DIM + col;
        out[idx] = hidden[idx] + (float)Gb[idx] * acc[f][n][j];
      }
    }
  }
}

// ---------------- memory update partials: part[sp][h] += K_h^T V_h over 1024 tokens ----------------
__global__ void __launch_bounds__(256)
mem_update_kernel(const __bf16* __restrict__ Y, float* __restrict__ part) {
  const int h = blockIdx.x & 15, sp = blockIdx.x >> 4;
  __shared__ __attribute__((aligned(16))) __bf16 KT[64 * 32];
  __shared__ __attribute__((aligned(16))) __bf16 VT[64 * 32];
  const int tid = threadIdx.x, wid = tid >> 6, lane = tid & 63;
  const int lrow = lane & 15, lk = (lane >> 4) * 8;
  const __bf16* Kbase = Y + (size_t)sp * 1024 * NKVQ + h * 64;
  const __bf16* Vbase = Kbase + 1024;
  f32x4 acc[4] = {};
  const int t = tid >> 3, c8 = (tid & 7) * 8;
  for (int t0 = 0; t0 < 1024; t0 += 32) {
    __syncthreads();
    bf16x8 kv = *(const bf16x8*)(Kbase + (size_t)(t0 + t) * NKVQ + c8);
    bf16x8 vv = *(const bf16x8*)(Vbase + (size_t)(t0 + t) * NKVQ + c8);
    #pragma unroll
    for (int j = 0; j < 8; ++j) {
      KT[(c8 + j) * 32 + t] = kv[j];
      VT[(c8 + j) * 32 + t] = vv[j];
    }
    __syncthreads();
    bf16x8 af = *(const bf16x8*)(KT + (wid * 16 + lrow) * 32 + lk);
    #pragma unroll
    for (int n = 0; n < 4; ++n) {
      bf16x8 bf_ = *(const bf16x8*)(VT + (n * 16 + lrow) * 32 + lk);
      acc[n] = __builtin_amdgcn_mfma_f32_16x16x32_bf16(af, bf_, acc[n], 0, 0, 0);
    }
  }
  float* pp = part + ((size_t)sp * 16 + h) * 4096;
  const int crow = wid * 16 + (lane >> 4) * 4, ccol = lane & 15;
  #pragma unroll
  for (int n = 0; n < 4; ++n)
    #pragma unroll
    for (int r = 0; r < 4; ++r)
      pp[(crow + r) * 64 + n * 16 + ccol] = acc[n][r];
}

// ---------------- memory reduce: out = 0.99*mem + sum_sp part ----------------
__global__ void mem_reduce_kernel(const float* __restrict__ part, const float* __restrict__ mem,
                                  float* __restrict__ out) {
  int i = blockIdx.x * blockDim.x + threadIdx.x;
  float s = 0.99f * mem[i];
  #pragma unroll
  for (int sp = 0; sp < 16; ++sp) s += part[sp * 65536 + i];
  out[i] = s;
}

extern "C" void kernel_launch(void* const* d_in, const int* in_sizes, int n_in,
                              void* d_out, int out_size, void* d_ws, size_t ws_size,
                              hipStream_t stream) {
  const float* hidden = (const float*)d_in[0];
  const float* memory = (const float*)d_in[1];
  const float* Wk = (const float*)d_in[2];
  const float* Wv = (const float*)d_in[3];
  const float* Wq = (const float*)d_in[4];
  const float* Wg = (const float*)d_in[5];
  const float* Wo = (const float*)d_in[6];
  float* out = (float*)d_out;
  float* mem_out = out + (size_t)TOKENS * DIM;

  char* ws = (char*)d_ws;
  __bf16* Xb   = (__bf16*)(ws);                    // 16384x2048  (67,108,864 B)
  __bf16* W1   = (__bf16*)(ws + 67108864);         // 5120x2048   (20,971,520 B)
  __bf16* Weff = (__bf16*)(ws + 88080384);         // 2048x1024   ( 4,194,304 B)
  __bf16* Yb   = (__bf16*)(ws + 92274688);         // 16384x3072  (100,663,296 B)
  __bf16* Gb   = (__bf16*)(ws + 192937984);        // 16384x2048  (67,108,864 B)
  float*  part = (float*)(ws + 260046848);         // 16x16x64x64 ( 4,194,304 B)

  cast8_kernel<<<16384, 256, 0, stream>>>(hidden, Xb, 4194304);
  cast8_kernel<<<1024, 256, 0, stream>>>(Wk, W1, 262144);
  cast8_kernel<<<1024, 256, 0, stream>>>(Wv, W1 + 2097152, 262144);
  cast8_kernel<<<1024, 256, 0, stream>>>(Wq, W1 + 4194304, 262144);
  cast8_kernel<<<2048, 256, 0, stream>>>(Wg, W1 + 6291456, 524288);
  weff_kernel<<<8192, 256, 0, stream>>>(Wo, memory, Weff);

  gemm_fused_kernel<<<1280, 512, 0, stream>>>(Xb, W1, Yb, Gb);
  gemm_read_kernel<<<512, 512, 0, stream>>>(Yb + 2048, Weff, Gb, hidden, out);

  mem_update_kernel<<<256, 256, 0, stream>>>(Yb, part);
  mem_reduce_kernel<<<256, 256, 0, stream>>>(part, memory, mem_out);
}